// Round 2
// baseline (2892.338 us; speedup 1.0000x reference)
//
#include <hip/hip_runtime.h>
#include <hip/hip_bf16.h>

// Problem constants
// B=2, S=2048, D=1024, H=16, DK=64, THETA=10000
// Inputs (fp32 except positions): x[2,2048,1024], token_positions[2048] (int32),
// Wq,Wk,Wv,Wo [1024,1024].  Output fp32 [2,2048,1024].
// proj: y[b,s,o] = sum_d x[b,s,d] * W[o,d]   (i.e. x @ W^T, both row-major)

typedef __attribute__((ext_vector_type(8))) short short8;   // 8 bf16 = 4 VGPRs
typedef __attribute__((ext_vector_type(4))) float floatx4;  // MFMA accumulator

// ---------------------------------------------------------------------------
// Kernel A: fp32 -> bf16 conversion (vectorized 4-wide)
// ---------------------------------------------------------------------------
__global__ __launch_bounds__(256) void cvt_bf16(const float4* __restrict__ src,
                                                ushort4* __restrict__ dst, int n4) {
  int i = blockIdx.x * 256 + threadIdx.x;
  if (i < n4) {
    float4 v = src[i];
    __hip_bfloat16 a = __float2bfloat16(v.x);
    __hip_bfloat16 b = __float2bfloat16(v.y);
    __hip_bfloat16 c = __float2bfloat16(v.z);
    __hip_bfloat16 d = __float2bfloat16(v.w);
    ushort4 o;
    o.x = *(unsigned short*)&a;
    o.y = *(unsigned short*)&b;
    o.z = *(unsigned short*)&c;
    o.w = *(unsigned short*)&d;
    dst[i] = o;
  }
}

// ---------------------------------------------------------------------------
// Kernel 0: RoPE cos/sin tables, fp32, indexed [s][i], i = pair index 0..31
// ---------------------------------------------------------------------------
__global__ void rope_tables(const int* __restrict__ tokpos,
                            float* __restrict__ ctab, float* __restrict__ stab) {
  int idx = blockIdx.x * 256 + threadIdx.x;     // 2048*32 = 65536
  int s = idx >> 5;
  int i = idx & 31;
  // log(10000) = 9.210340371976184
  float inv = expf(-9.210340371976184f * (float)(2 * i) / 64.0f);
  float ang = (float)tokpos[s] * inv;
  ctab[idx] = cosf(ang);
  stab[idx] = sinf(ang);
}

// ---------------------------------------------------------------------------
// Kernel 1: QKV projection, MFMA 16x16x32 bf16, one 16x16 tile per wave.
// RoPE applied in epilogue for q,k (pair exchange via shfl_xor(1)).
// Outputs fp32 in [B*H][S][DK] layout.
// ---------------------------------------------------------------------------
__global__ __launch_bounds__(256) void qkv_mfma(
    const __hip_bfloat16* __restrict__ X,
    const __hip_bfloat16* __restrict__ Wq,
    const __hip_bfloat16* __restrict__ Wk,
    const __hip_bfloat16* __restrict__ Wv,
    const float* __restrict__ ctab, const float* __restrict__ stab,
    float* __restrict__ Qo, float* __restrict__ Ko, float* __restrict__ Vo) {
  int wave = threadIdx.x >> 6;
  int lane = threadIdx.x & 63;
  int mtile = blockIdx.x;                 // 0..255  (rows of x, flat b*S+s)
  int ntile = blockIdx.y * 4 + wave;      // 0..63   (output cols)
  int mat = blockIdx.z;                   // 0=q 1=k 2=v

  const __hip_bfloat16* W = (mat == 0) ? Wq : ((mat == 1) ? Wk : Wv);
  float* Out = (mat == 0) ? Qo : ((mat == 1) ? Ko : Vo);

  int l15 = lane & 15;
  int quad = lane >> 4;
  // A frag: A[m = lane&15][k = quad*8 + j]  (8 contiguous bf16)
  // B frag: B[k = quad*8 + j][n = lane&15]; B[k][n] = W[n][k] -> contiguous row read
  const short8* ap = (const short8*)(X + (size_t)(mtile * 16 + l15) * 1024 + quad * 8);
  const short8* bp = (const short8*)(W + (size_t)(ntile * 16 + l15) * 1024 + quad * 8);

  floatx4 acc = {0.f, 0.f, 0.f, 0.f};
#pragma unroll 8
  for (int kt = 0; kt < 32; ++kt) {
    acc = __builtin_amdgcn_mfma_f32_16x16x32_bf16(ap[kt * 4], bp[kt * 4], acc, 0, 0, 0);
  }

  int col = ntile * 16 + l15;   // 0..1023
  int h = col >> 6;
  int d = col & 63;
  int pi = d >> 1;
  bool odd = (d & 1) != 0;

#pragma unroll
  for (int i = 0; i < 4; ++i) {
    int row = mtile * 16 + quad * 4 + i;  // C/D: row = quad*4 + reg, col = lane&15
    int b = row >> 11;
    int s = row & 2047;
    float v = acc[i];
    float res;
    if (mat == 2) {
      res = v;
    } else {
      float p = __shfl_xor(v, 1);  // partner column (other half of rope pair)
      float c = ctab[s * 32 + pi];
      float sn = stab[s * 32 + pi];
      // even col: r1 = x1*c - x2*sn (v=x1, p=x2); odd col: r2 = x1*sn + x2*c (p=x1, v=x2)
      res = odd ? fmaf(p, sn, v * c) : fmaf(v, c, -p * sn);
    }
    Out[((size_t)(b * 16 + h) * 2048 + s) * 64 + d] = res;
  }
}

// ---------------------------------------------------------------------------
// Kernel 2: causal attention, one wave per (b,h,q) row, fp32 vector math.
// Two-pass softmax with score row in LDS. Writes O as bf16 in [B*S][D] layout
// (head-concat), ready for the output projection GEMM.
// ---------------------------------------------------------------------------
__global__ __launch_bounds__(64) void attn_row(
    const float* __restrict__ Q, const float* __restrict__ K,
    const float* __restrict__ V, __hip_bfloat16* __restrict__ Oc) {
  __shared__ float sc[2048];
  int lane = threadIdx.x;
  int q = blockIdx.x;    // 0..2047
  int bh = blockIdx.y;   // 0..31
  size_t base = (size_t)bh * 2048 * 64;

  // q row into registers (64 floats)
  const float4* qr = (const float4*)(Q + base + (size_t)q * 64);
  float4 qv[16];
#pragma unroll
  for (int j = 0; j < 16; ++j) qv[j] = qr[j];

  // pass 1: scores + max
  float mx = -1e30f;
  for (int k = lane; k <= q; k += 64) {
    const float4* kr = (const float4*)(K + base + (size_t)k * 64);
    float s = 0.f;
#pragma unroll
    for (int j = 0; j < 16; ++j) {
      float4 kv = kr[j];
      s += qv[j].x * kv.x + qv[j].y * kv.y + qv[j].z * kv.z + qv[j].w * kv.w;
    }
    s *= 0.125f;  // 1/sqrt(64)
    sc[k] = s;
    mx = fmaxf(mx, s);
  }
#pragma unroll
  for (int off = 32; off; off >>= 1) mx = fmaxf(mx, __shfl_xor(mx, off));

  __syncthreads();

  // pass 2: exp + sum
  float sum = 0.f;
  for (int k = lane; k <= q; k += 64) {
    float e = __expf(sc[k] - mx);
    sc[k] = e;
    sum += e;
  }
#pragma unroll
  for (int off = 32; off; off >>= 1) sum += __shfl_xor(sum, off);

  __syncthreads();

  // pass 3: O[d] = (1/sum) * sum_k p[k] * V[k][d]; lane == d, coalesced V reads
  float inv = 1.f / sum;
  float acc = 0.f;
  int n = q + 1;
  const float* vp = V + base + lane;
  int k = 0;
  for (; k + 4 <= n; k += 4) {
    acc = fmaf(sc[k + 0], vp[(size_t)(k + 0) * 64], acc);
    acc = fmaf(sc[k + 1], vp[(size_t)(k + 1) * 64], acc);
    acc = fmaf(sc[k + 2], vp[(size_t)(k + 2) * 64], acc);
    acc = fmaf(sc[k + 3], vp[(size_t)(k + 3) * 64], acc);
  }
  for (; k < n; ++k) acc = fmaf(sc[k], vp[(size_t)k * 64], acc);

  int b = bh >> 4;
  int h = bh & 15;
  Oc[((size_t)(b * 2048 + q)) * 1024 + h * 64 + lane] = __float2bfloat16(acc * inv);
}

// ---------------------------------------------------------------------------
// Kernel 3: output projection: out = Oc @ Wo^T, bf16 MFMA, fp32 store
// ---------------------------------------------------------------------------
__global__ __launch_bounds__(256) void oproj_mfma(
    const __hip_bfloat16* __restrict__ A, const __hip_bfloat16* __restrict__ Wo,
    float* __restrict__ Out) {
  int wave = threadIdx.x >> 6;
  int lane = threadIdx.x & 63;
  int mtile = blockIdx.x;
  int ntile = blockIdx.y * 4 + wave;
  int l15 = lane & 15;
  int quad = lane >> 4;
  const short8* ap = (const short8*)(A + (size_t)(mtile * 16 + l15) * 1024 + quad * 8);
  const short8* bp = (const short8*)(Wo + (size_t)(ntile * 16 + l15) * 1024 + quad * 8);
  floatx4 acc = {0.f, 0.f, 0.f, 0.f};
#pragma unroll 8
  for (int kt = 0; kt < 32; ++kt) {
    acc = __builtin_amdgcn_mfma_f32_16x16x32_bf16(ap[kt * 4], bp[kt * 4], acc, 0, 0, 0);
  }
  int col = ntile * 16 + l15;
#pragma unroll
  for (int i = 0; i < 4; ++i) {
    int row = mtile * 16 + quad * 4 + i;
    Out[(size_t)row * 1024 + col] = acc[i];
  }
}

// ---------------------------------------------------------------------------
extern "C" void kernel_launch(void* const* d_in, const int* in_sizes, int n_in,
                              void* d_out, int out_size, void* d_ws, size_t ws_size,
                              hipStream_t stream) {
  const float* x  = (const float*)d_in[0];
  const int* tokpos = (const int*)d_in[1];
  const float* Wq = (const float*)d_in[2];
  const float* Wk = (const float*)d_in[3];
  const float* Wv = (const float*)d_in[4];
  const float* Wo = (const float*)d_in[5];
  float* out = (float*)d_out;

  // Workspace layout (fp32 words):
  // ctab 64K | stab 64K | Q 4M | K 4M | V 4M | Oc(bf16,2M words) | xb(bf16,2M)
  // | Wqb,Wkb,Wvb,Wob (bf16, 512K words each)  -> total ~76 MB
  float* ws = (float*)d_ws;
  float* ctab = ws;
  float* stab = ctab + 65536;
  float* Q = stab + 65536;
  float* K = Q + 4194304;
  float* V = K + 4194304;
  __hip_bfloat16* Oc  = (__hip_bfloat16*)(V + 4194304);
  __hip_bfloat16* xb  = (__hip_bfloat16*)(V + 4194304 + 2097152);
  __hip_bfloat16* Wqb = (__hip_bfloat16*)(V + 4194304 + 2 * 2097152);
  __hip_bfloat16* Wkb = Wqb + 1048576;
  __hip_bfloat16* Wvb = Wkb + 1048576;
  __hip_bfloat16* Wob = Wvb + 1048576;

  // fp32 -> bf16 conversions
  cvt_bf16<<<4096, 256, 0, stream>>>((const float4*)x,  (ushort4*)xb,  1048576);
  cvt_bf16<<<1024, 256, 0, stream>>>((const float4*)Wq, (ushort4*)Wqb, 262144);
  cvt_bf16<<<1024, 256, 0, stream>>>((const float4*)Wk, (ushort4*)Wkb, 262144);
  cvt_bf16<<<1024, 256, 0, stream>>>((const float4*)Wv, (ushort4*)Wvb, 262144);
  cvt_bf16<<<1024, 256, 0, stream>>>((const float4*)Wo, (ushort4*)Wob, 262144);

  rope_tables<<<256, 256, 0, stream>>>(tokpos, ctab, stab);
  qkv_mfma<<<dim3(256, 16, 3), 256, 0, stream>>>(xb, Wqb, Wkb, Wvb, ctab, stab, Q, K, V);
  attn_row<<<dim3(2048, 32), 64, 0, stream>>>(Q, K, V, Oc);
  oproj_mfma<<<dim3(256, 16), 256, 0, stream>>>(Oc, Wob, out);
}

// Round 3
// 666.611 us; speedup vs baseline: 4.3389x; 4.3389x over previous
//
#include <hip/hip_runtime.h>
#include <hip/hip_bf16.h>

// B=2, S=2048, D=1024, H=16, DK=64, THETA=10000
// Inputs fp32 (positions int32): x[2,2048,1024], token_positions[2048],
// Wq,Wk,Wv,Wo [1024,1024].  Output fp32 [2,2048,1024].
// proj: y[b,s,o] = sum_d x[b,s,d] * W[o,d]

typedef __attribute__((ext_vector_type(8))) short short8;   // 8 bf16 = 4 VGPRs
typedef __attribute__((ext_vector_type(4))) float floatx4;  // MFMA accumulator

static __device__ __forceinline__ unsigned short f2bf(float f) {
  __hip_bfloat16 h = __float2bfloat16(f);
  return *(unsigned short*)&h;
}

// ---------------------------------------------------------------------------
// fp32 -> bf16 conversion (vectorized 4-wide)
// ---------------------------------------------------------------------------
__global__ __launch_bounds__(256) void cvt_bf16(const float4* __restrict__ src,
                                                ushort4* __restrict__ dst, int n4) {
  int i = blockIdx.x * 256 + threadIdx.x;
  if (i < n4) {
    float4 v = src[i];
    ushort4 o;
    o.x = f2bf(v.x); o.y = f2bf(v.y); o.z = f2bf(v.z); o.w = f2bf(v.w);
    dst[i] = o;
  }
}

// ---------------------------------------------------------------------------
// RoPE cos/sin tables, fp32, [s][pair 0..31]
// ---------------------------------------------------------------------------
__global__ void rope_tables(const int* __restrict__ tokpos,
                            float* __restrict__ ctab, float* __restrict__ stab) {
  int idx = blockIdx.x * 256 + threadIdx.x;  // 65536
  int s = idx >> 5;
  int i = idx & 31;
  float inv = expf(-9.210340371976184f * (float)(2 * i) / 64.0f);
  float ang = (float)tokpos[s] * inv;
  ctab[idx] = cosf(ang);
  stab[idx] = sinf(ang);
}

// ---------------------------------------------------------------------------
// QKV projection, MFMA 16x16x32 bf16, RoPE fused for q/k.
// Outputs bf16: Q,K in [bh][s][64]; V transposed in [bh][d][s=2048].
// ---------------------------------------------------------------------------
__global__ __launch_bounds__(256) void qkv_mfma(
    const __hip_bfloat16* __restrict__ X,
    const __hip_bfloat16* __restrict__ Wq,
    const __hip_bfloat16* __restrict__ Wk,
    const __hip_bfloat16* __restrict__ Wv,
    const float* __restrict__ ctab, const float* __restrict__ stab,
    unsigned short* __restrict__ Qo, unsigned short* __restrict__ Ko,
    unsigned short* __restrict__ Vo) {
  int wave = threadIdx.x >> 6;
  int lane = threadIdx.x & 63;
  int mtile = blockIdx.x;                 // 0..255
  int ntile = blockIdx.y * 4 + wave;      // 0..63
  int mat = blockIdx.z;                   // 0=q 1=k 2=v

  const __hip_bfloat16* W = (mat == 0) ? Wq : ((mat == 1) ? Wk : Wv);
  unsigned short* Out = (mat == 0) ? Qo : ((mat == 1) ? Ko : Vo);

  int l15 = lane & 15;
  int quad = lane >> 4;
  const short8* ap = (const short8*)(X + (size_t)(mtile * 16 + l15) * 1024 + quad * 8);
  const short8* bp = (const short8*)(W + (size_t)(ntile * 16 + l15) * 1024 + quad * 8);

  floatx4 acc = {0.f, 0.f, 0.f, 0.f};
#pragma unroll 8
  for (int kt = 0; kt < 32; ++kt) {
    acc = __builtin_amdgcn_mfma_f32_16x16x32_bf16(ap[kt * 4], bp[kt * 4], acc, 0, 0, 0);
  }

  int col = ntile * 16 + l15;   // 0..1023
  int h = col >> 6;
  int d = col & 63;
  int pi = d >> 1;
  bool odd = (d & 1) != 0;

#pragma unroll
  for (int i = 0; i < 4; ++i) {
    int row = mtile * 16 + quad * 4 + i;
    int b = row >> 11;
    int s = row & 2047;
    float v = acc[i];
    float res;
    if (mat == 2) {
      res = v;
    } else {
      float p = __shfl_xor(v, 1);
      float c = ctab[s * 32 + pi];
      float sn = stab[s * 32 + pi];
      res = odd ? fmaf(p, sn, v * c) : fmaf(v, c, -p * sn);
    }
    size_t base = (size_t)(b * 16 + h) * 2048 * 64;
    size_t idx = (mat == 2) ? (base + (size_t)d * 2048 + s)
                            : (base + (size_t)s * 64 + d);
    Out[idx] = f2bf(res);
  }
}

// ---------------------------------------------------------------------------
// Flash attention: block = 4 waves, 64-row Q tile, 64-col K/V tiles in LDS.
// Online softmax, P round-trip through LDS (C-layout -> A-layout).
// Q,K: bf16 [bh][s][64]; Vt: bf16 [bh][d][2048]; Oc: bf16 [b*s][1024].
// ---------------------------------------------------------------------------
#define LKS 72  // padded LDS row stride (elements) -> breaks bank conflicts

__global__ __launch_bounds__(256) void attn_flash(
    const unsigned short* __restrict__ Q, const unsigned short* __restrict__ K,
    const unsigned short* __restrict__ Vt, unsigned short* __restrict__ Oc) {
  __shared__ unsigned short lK[64 * LKS];      // [kj][d]
  __shared__ unsigned short lV[64 * LKS];      // [d][kj]
  __shared__ unsigned short lP[4][16 * LKS];   // per-wave [row][kj]

  int tid = threadIdx.x;
  int wave = tid >> 6, lane = tid & 63;
  int l15 = lane & 15, quad = lane >> 4;
  int qtile = 31 - blockIdx.x;   // heavy tiles dispatch first
  int bh = blockIdx.y;
  size_t base = (size_t)bh * 2048 * 64;
  int qbase = qtile * 64;

  // Q fragments (constant across k loop): rows qbase + wave*16 + l15
  const unsigned short* qrow = Q + base + (size_t)(qbase + wave * 16 + l15) * 64;
  short8 qa0 = *(const short8*)(qrow + quad * 8);
  short8 qa1 = *(const short8*)(qrow + 32 + quad * 8);

  floatx4 o[4];
  float m_i[4], l_i[4];
#pragma unroll
  for (int i = 0; i < 4; ++i) {
    o[i] = (floatx4){0.f, 0.f, 0.f, 0.f};
    m_i[i] = -1e30f;
    l_i[i] = 0.f;
  }

  for (int kt = 0; kt <= qtile; ++kt) {
    int kbase = kt * 64;
    // ---- stage K tile [64][64] and Vt tile [64][64] into LDS (bf16 copies)
    {
      const unsigned short* ks = K + base + (size_t)kbase * 64;
      const unsigned short* vs = Vt + base + kbase;
#pragma unroll
      for (int p = 0; p < 2; ++p) {
        int c = p * 256 + tid;           // 0..511
        int r = c >> 3, e0 = (c & 7) * 8;
        *(short8*)(lK + r * LKS + e0) = *(const short8*)(ks + r * 64 + e0);
        *(short8*)(lV + r * LKS + e0) = *(const short8*)(vs + (size_t)r * 2048 + e0);
      }
    }
    __syncthreads();

    // ---- QK^T: 4 subtiles of 16 cols, contraction d=64 via 2 MFMAs
    float sc[4][4];
#pragma unroll
    for (int sub = 0; sub < 4; ++sub) {
      const unsigned short* kr = lK + (sub * 16 + l15) * LKS + quad * 8;
      short8 b0 = *(const short8*)(kr);
      short8 b1 = *(const short8*)(kr + 32);
      floatx4 s = {0.f, 0.f, 0.f, 0.f};
      s = __builtin_amdgcn_mfma_f32_16x16x32_bf16(qa0, b0, s, 0, 0, 0);
      s = __builtin_amdgcn_mfma_f32_16x16x32_bf16(qa1, b1, s, 0, 0, 0);
#pragma unroll
      for (int i = 0; i < 4; ++i) sc[sub][i] = s[i] * 0.125f;  // 1/sqrt(64)
    }

    // ---- causal mask (diagonal tile only)
    if (kt == qtile) {
#pragma unroll
      for (int sub = 0; sub < 4; ++sub)
#pragma unroll
        for (int i = 0; i < 4; ++i)
          if (sub * 16 + l15 > wave * 16 + quad * 4 + i) sc[sub][i] = -1e30f;
    }

    // ---- online softmax update (state per q-row; rows = quad*4+i)
#pragma unroll
    for (int i = 0; i < 4; ++i) {
      float mb = fmaxf(fmaxf(sc[0][i], sc[1][i]), fmaxf(sc[2][i], sc[3][i]));
#pragma unroll
      for (int off = 1; off < 16; off <<= 1) mb = fmaxf(mb, __shfl_xor(mb, off));
      float mn = fmaxf(m_i[i], mb);
      float al = __expf(m_i[i] - mn);
      m_i[i] = mn;
      float rs = 0.f;
#pragma unroll
      for (int sub = 0; sub < 4; ++sub) {
        float pv = __expf(sc[sub][i] - mn);
        sc[sub][i] = pv;
        rs += pv;
      }
#pragma unroll
      for (int off = 1; off < 16; off <<= 1) rs += __shfl_xor(rs, off);
      l_i[i] = l_i[i] * al + rs;
#pragma unroll
      for (int n = 0; n < 4; ++n) o[n][i] *= al;
    }

    // ---- P (C-layout) -> per-wave LDS -> A-layout fragments
    unsigned short* pw = lP[wave];
#pragma unroll
    for (int sub = 0; sub < 4; ++sub)
#pragma unroll
      for (int i = 0; i < 4; ++i)
        pw[(quad * 4 + i) * LKS + sub * 16 + l15] = f2bf(sc[sub][i]);

    const unsigned short* pr = pw + l15 * LKS + quad * 8;
    short8 pa0 = *(const short8*)(pr);
    short8 pa1 = *(const short8*)(pr + 32);

    // ---- PV: O[16][64] += P[16][64] * V[64][64]
#pragma unroll
    for (int n = 0; n < 4; ++n) {
      const unsigned short* vr = lV + (n * 16 + l15) * LKS + quad * 8;
      short8 vb0 = *(const short8*)(vr);
      short8 vb1 = *(const short8*)(vr + 32);
      o[n] = __builtin_amdgcn_mfma_f32_16x16x32_bf16(pa0, vb0, o[n], 0, 0, 0);
      o[n] = __builtin_amdgcn_mfma_f32_16x16x32_bf16(pa1, vb1, o[n], 0, 0, 0);
    }
    __syncthreads();  // protect lK/lV before next staging
  }

  // ---- epilogue: O /= l, store bf16 head-concat [b*s][1024]
  int b = bh >> 4, h = bh & 15;
#pragma unroll
  for (int i = 0; i < 4; ++i) {
    float inv = 1.f / l_i[i];
    int s = qbase + wave * 16 + quad * 4 + i;
    size_t orow = (size_t)(b * 2048 + s) * 1024 + h * 64;
#pragma unroll
    for (int n = 0; n < 4; ++n)
      Oc[orow + n * 16 + l15] = f2bf(o[n][i] * inv);
  }
}

// ---------------------------------------------------------------------------
// Output projection: out = Oc @ Wo^T, bf16 MFMA, fp32 store
// ---------------------------------------------------------------------------
__global__ __launch_bounds__(256) void oproj_mfma(
    const unsigned short* __restrict__ A, const __hip_bfloat16* __restrict__ Wo,
    float* __restrict__ Out) {
  int wave = threadIdx.x >> 6;
  int lane = threadIdx.x & 63;
  int mtile = blockIdx.x;
  int ntile = blockIdx.y * 4 + wave;
  int l15 = lane & 15;
  int quad = lane >> 4;
  const short8* ap = (const short8*)(A + (size_t)(mtile * 16 + l15) * 1024 + quad * 8);
  const short8* bp = (const short8*)(Wo + (size_t)(ntile * 16 + l15) * 1024 + quad * 8);
  floatx4 acc = {0.f, 0.f, 0.f, 0.f};
#pragma unroll 8
  for (int kt = 0; kt < 32; ++kt) {
    acc = __builtin_amdgcn_mfma_f32_16x16x32_bf16(ap[kt * 4], bp[kt * 4], acc, 0, 0, 0);
  }
  int col = ntile * 16 + l15;
#pragma unroll
  for (int i = 0; i < 4; ++i) {
    int row = mtile * 16 + quad * 4 + i;
    Out[(size_t)row * 1024 + col] = acc[i];
  }
}

// ---------------------------------------------------------------------------
extern "C" void kernel_launch(void* const* d_in, const int* in_sizes, int n_in,
                              void* d_out, int out_size, void* d_ws, size_t ws_size,
                              hipStream_t stream) {
  const float* x  = (const float*)d_in[0];
  const int* tokpos = (const int*)d_in[1];
  const float* Wq = (const float*)d_in[2];
  const float* Wk = (const float*)d_in[3];
  const float* Wv = (const float*)d_in[4];
  const float* Wo = (const float*)d_in[5];
  float* out = (float*)d_out;

  // Workspace: ctab|stab fp32 (64K each), then bf16 region:
  // Qb,Kb,Vb,Oc,xb (4M elems each) | Wqb,Wkb,Wvb,Wob (1M each)  ~49 MB
  float* ws = (float*)d_ws;
  float* ctab = ws;
  float* stab = ctab + 65536;
  unsigned short* u = (unsigned short*)(stab + 65536);
  unsigned short* Qb  = u;
  unsigned short* Kb  = Qb + 4194304;
  unsigned short* Vb  = Kb + 4194304;   // transposed [bh][d][s]
  unsigned short* Oc  = Vb + 4194304;
  unsigned short* xb  = Oc + 4194304;
  unsigned short* Wqb = xb + 4194304;
  unsigned short* Wkb = Wqb + 1048576;
  unsigned short* Wvb = Wkb + 1048576;
  unsigned short* Wob = Wvb + 1048576;

  cvt_bf16<<<4096, 256, 0, stream>>>((const float4*)x,  (ushort4*)xb,  1048576);
  cvt_bf16<<<1024, 256, 0, stream>>>((const float4*)Wq, (ushort4*)Wqb, 262144);
  cvt_bf16<<<1024, 256, 0, stream>>>((const float4*)Wk, (ushort4*)Wkb, 262144);
  cvt_bf16<<<1024, 256, 0, stream>>>((const float4*)Wv, (ushort4*)Wvb, 262144);
  cvt_bf16<<<1024, 256, 0, stream>>>((const float4*)Wo, (ushort4*)Wob, 262144);

  rope_tables<<<256, 256, 0, stream>>>(tokpos, ctab, stab);
  qkv_mfma<<<dim3(256, 16, 3), 256, 0, stream>>>(
      (const __hip_bfloat16*)xb, (const __hip_bfloat16*)Wqb,
      (const __hip_bfloat16*)Wkb, (const __hip_bfloat16*)Wvb,
      ctab, stab, Qb, Kb, Vb);
  attn_flash<<<dim3(32, 32), 256, 0, stream>>>(Qb, Kb, Vb, Oc);
  oproj_mfma<<<dim3(256, 16), 256, 0, stream>>>(Oc, (const __hip_bfloat16*)Wob, out);
}

// Round 4
// 297.630 us; speedup vs baseline: 9.7179x; 2.2397x over previous
//
#include <hip/hip_runtime.h>
#include <hip/hip_bf16.h>

// B=2, S=2048, D=1024, H=16, DK=64, THETA=10000
// Inputs fp32 (positions int32): x[2,2048,1024], token_positions[2048],
// Wq,Wk,Wv,Wo [1024,1024].  Output fp32 [2,2048,1024].
// proj: y[b,s,o] = sum_d x[b,s,d] * W[o,d]

typedef __attribute__((ext_vector_type(8))) short short8;   // 8 bf16 = 4 VGPRs
typedef __attribute__((ext_vector_type(4))) float floatx4;  // MFMA accumulator

static __device__ __forceinline__ unsigned short f2bf(float f) {
  __hip_bfloat16 h = __float2bfloat16(f);
  return *(unsigned short*)&h;
}

#define LSTR 72  // LDS row stride (elements): 144B -> 2-way bank alias on reads (free)

// ---------------------------------------------------------------------------
// fp32 -> bf16 conversion (vectorized 4-wide)
// ---------------------------------------------------------------------------
__global__ __launch_bounds__(256) void cvt_bf16(const float4* __restrict__ src,
                                                ushort4* __restrict__ dst, int n4) {
  int i = blockIdx.x * 256 + threadIdx.x;
  if (i < n4) {
    float4 v = src[i];
    ushort4 o;
    o.x = f2bf(v.x); o.y = f2bf(v.y); o.z = f2bf(v.z); o.w = f2bf(v.w);
    dst[i] = o;
  }
}

// ---------------------------------------------------------------------------
// RoPE cos/sin tables, fp32, [s][pair 0..31]
// ---------------------------------------------------------------------------
__global__ void rope_tables(const int* __restrict__ tokpos,
                            float* __restrict__ ctab, float* __restrict__ stab) {
  int idx = blockIdx.x * 256 + threadIdx.x;  // 65536
  int s = idx >> 5;
  int i = idx & 31;
  float inv = expf(-9.210340371976184f * (float)(2 * i) / 64.0f);
  float ang = (float)tokpos[s] * inv;
  ctab[idx] = cosf(ang);
  stab[idx] = sinf(ang);
}

// ---------------------------------------------------------------------------
// Shared 128x128-tile GEMM body: C[128][128] = A[128x1024] * W^T (both row-major).
// 4 waves in 2x2; each wave 64x64 = 4x4 MFMA subtiles. BK=64, LDS staged.
// Leaves 16 floatx4 accumulators in acc[][]; caller does the epilogue.
// ---------------------------------------------------------------------------
#define GEMM128_BODY(Aptr, Wptr, m0, n0)                                        \
  __shared__ unsigned short lA[128 * LSTR];                                     \
  __shared__ unsigned short lB[128 * LSTR];                                     \
  int tid = threadIdx.x;                                                        \
  int wave = tid >> 6, lane = tid & 63;                                         \
  int wm = wave >> 1, wn = wave & 1;                                            \
  int l15 = lane & 15, quad = lane >> 4;                                        \
  floatx4 acc[4][4];                                                            \
  _Pragma("unroll") for (int m = 0; m < 4; ++m)                                 \
      _Pragma("unroll") for (int n = 0; n < 4; ++n)                             \
          acc[m][n] = (floatx4){0.f, 0.f, 0.f, 0.f};                            \
  for (int kt = 0; kt < 16; ++kt) {                                             \
    _Pragma("unroll") for (int p = 0; p < 4; ++p) {                             \
      int c = p * 256 + tid;            /* 0..1023: 128 rows x 8 chunks */      \
      int r = c >> 3, ch = (c & 7) * 8;                                         \
      *(short8*)(lA + r * LSTR + ch) =                                          \
          *(const short8*)(Aptr + (size_t)(m0 + r) * 1024 + kt * 64 + ch);      \
      *(short8*)(lB + r * LSTR + ch) =                                          \
          *(const short8*)(Wptr + (size_t)(n0 + r) * 1024 + kt * 64 + ch);      \
    }                                                                           \
    __syncthreads();                                                            \
    _Pragma("unroll") for (int ks = 0; ks < 2; ++ks) {                          \
      short8 af[4], bf[4];                                                      \
      _Pragma("unroll") for (int m = 0; m < 4; ++m)                             \
          af[m] = *(const short8*)(lA + (wm * 64 + m * 16 + l15) * LSTR +       \
                                   ks * 32 + quad * 8);                         \
      _Pragma("unroll") for (int n = 0; n < 4; ++n)                             \
          bf[n] = *(const short8*)(lB + (wn * 64 + n * 16 + l15) * LSTR +       \
                                   ks * 32 + quad * 8);                         \
      _Pragma("unroll") for (int m = 0; m < 4; ++m)                             \
          _Pragma("unroll") for (int n = 0; n < 4; ++n)                         \
              acc[m][n] = __builtin_amdgcn_mfma_f32_16x16x32_bf16(              \
                  af[m], bf[n], acc[m][n], 0, 0, 0);                            \
    }                                                                           \
    __syncthreads();                                                            \
  }

// ---------------------------------------------------------------------------
// QKV projection, tiled MFMA GEMM + fused RoPE epilogue.
// Outputs bf16: Q,K in [bh][s][64]; V transposed in [bh][d][2048].
// ---------------------------------------------------------------------------
__global__ __launch_bounds__(256) void qkv_mfma(
    const unsigned short* __restrict__ X,
    const unsigned short* __restrict__ Wq,
    const unsigned short* __restrict__ Wk,
    const unsigned short* __restrict__ Wv,
    const float* __restrict__ ctab, const float* __restrict__ stab,
    unsigned short* __restrict__ Qo, unsigned short* __restrict__ Ko,
    unsigned short* __restrict__ Vo) {
  int mat = blockIdx.z;  // 0=q 1=k 2=v
  const unsigned short* W = (mat == 0) ? Wq : ((mat == 1) ? Wk : Wv);
  unsigned short* Out = (mat == 0) ? Qo : ((mat == 1) ? Ko : Vo);
  int m0 = blockIdx.x * 128, n0 = blockIdx.y * 128;

  GEMM128_BODY(X, W, m0, n0)

  // epilogue: RoPE (q,k) + scatter to head layouts
#pragma unroll
  for (int n = 0; n < 4; ++n) {
    int col = n0 + wn * 64 + n * 16 + l15;  // 0..1023
    int h = col >> 6;
    int d = col & 63;
    int pi = d >> 1;
    bool odd = (d & 1) != 0;
    size_t hb = (size_t)h * 2048 * 64;  // b added below
#pragma unroll
    for (int m = 0; m < 4; ++m) {
#pragma unroll
      for (int i = 0; i < 4; ++i) {
        int row = m0 + wm * 64 + m * 16 + quad * 4 + i;
        int b = row >> 11;
        int s = row & 2047;
        float v = acc[m][n][i];
        float res;
        if (mat == 2) {
          res = v;
        } else {
          float p = __shfl_xor(v, 1);
          float c = ctab[s * 32 + pi];
          float sn = stab[s * 32 + pi];
          res = odd ? fmaf(p, sn, v * c) : fmaf(v, c, -p * sn);
        }
        size_t base = (size_t)b * 16 * 2048 * 64 + hb;
        size_t idx = (mat == 2) ? (base + (size_t)d * 2048 + s)
                                : (base + (size_t)s * 64 + d);
        Out[idx] = f2bf(res);
      }
    }
  }
}

// ---------------------------------------------------------------------------
// Output projection: out = Oc @ Wo^T, tiled MFMA GEMM, fp32 store
// ---------------------------------------------------------------------------
__global__ __launch_bounds__(256) void oproj_mfma(
    const unsigned short* __restrict__ A, const unsigned short* __restrict__ Wo,
    float* __restrict__ Out) {
  int m0 = blockIdx.x * 128, n0 = blockIdx.y * 128;

  GEMM128_BODY(A, Wo, m0, n0)

#pragma unroll
  for (int m = 0; m < 4; ++m) {
#pragma unroll
    for (int n = 0; n < 4; ++n) {
      int col = n0 + wn * 64 + n * 16 + l15;
#pragma unroll
      for (int i = 0; i < 4; ++i) {
        int row = m0 + wm * 64 + m * 16 + quad * 4 + i;
        Out[(size_t)row * 1024 + col] = acc[m][n][i];
      }
    }
  }
}

// ---------------------------------------------------------------------------
// Flash attention: block = 4 waves, 64-row Q tile, 64-col K/V tiles in LDS.
// Online softmax, P round-trip through LDS (C-layout -> A-layout).
// Q,K: bf16 [bh][s][64]; Vt: bf16 [bh][d][2048]; Oc: bf16 [b*s][1024].
// ---------------------------------------------------------------------------
#define LKS 72

__global__ __launch_bounds__(256) void attn_flash(
    const unsigned short* __restrict__ Q, const unsigned short* __restrict__ K,
    const unsigned short* __restrict__ Vt, unsigned short* __restrict__ Oc) {
  __shared__ unsigned short lK[64 * LKS];      // [kj][d]
  __shared__ unsigned short lV[64 * LKS];      // [d][kj]
  __shared__ unsigned short lP[4][16 * LKS];   // per-wave [row][kj]

  int tid = threadIdx.x;
  int wave = tid >> 6, lane = tid & 63;
  int l15 = lane & 15, quad = lane >> 4;
  int qtile = 31 - blockIdx.x;   // heavy tiles dispatch first
  int bh = blockIdx.y;
  size_t base = (size_t)bh * 2048 * 64;
  int qbase = qtile * 64;

  const unsigned short* qrow = Q + base + (size_t)(qbase + wave * 16 + l15) * 64;
  short8 qa0 = *(const short8*)(qrow + quad * 8);
  short8 qa1 = *(const short8*)(qrow + 32 + quad * 8);

  floatx4 o[4];
  float m_i[4], l_i[4];
#pragma unroll
  for (int i = 0; i < 4; ++i) {
    o[i] = (floatx4){0.f, 0.f, 0.f, 0.f};
    m_i[i] = -1e30f;
    l_i[i] = 0.f;
  }

  for (int kt = 0; kt <= qtile; ++kt) {
    int kbase = kt * 64;
    {
      const unsigned short* ks = K + base + (size_t)kbase * 64;
      const unsigned short* vs = Vt + base + kbase;
#pragma unroll
      for (int p = 0; p < 2; ++p) {
        int c = p * 256 + tid;           // 0..511
        int r = c >> 3, e0 = (c & 7) * 8;
        *(short8*)(lK + r * LKS + e0) = *(const short8*)(ks + r * 64 + e0);
        *(short8*)(lV + r * LKS + e0) = *(const short8*)(vs + (size_t)r * 2048 + e0);
      }
    }
    __syncthreads();

    float sc[4][4];
#pragma unroll
    for (int sub = 0; sub < 4; ++sub) {
      const unsigned short* kr = lK + (sub * 16 + l15) * LKS + quad * 8;
      short8 b0 = *(const short8*)(kr);
      short8 b1 = *(const short8*)(kr + 32);
      floatx4 s = {0.f, 0.f, 0.f, 0.f};
      s = __builtin_amdgcn_mfma_f32_16x16x32_bf16(qa0, b0, s, 0, 0, 0);
      s = __builtin_amdgcn_mfma_f32_16x16x32_bf16(qa1, b1, s, 0, 0, 0);
#pragma unroll
      for (int i = 0; i < 4; ++i) sc[sub][i] = s[i] * 0.125f;
    }

    if (kt == qtile) {
#pragma unroll
      for (int sub = 0; sub < 4; ++sub)
#pragma unroll
        for (int i = 0; i < 4; ++i)
          if (sub * 16 + l15 > wave * 16 + quad * 4 + i) sc[sub][i] = -1e30f;
    }

#pragma unroll
    for (int i = 0; i < 4; ++i) {
      float mb = fmaxf(fmaxf(sc[0][i], sc[1][i]), fmaxf(sc[2][i], sc[3][i]));
#pragma unroll
      for (int off = 1; off < 16; off <<= 1) mb = fmaxf(mb, __shfl_xor(mb, off));
      float mn = fmaxf(m_i[i], mb);
      float al = __expf(m_i[i] - mn);
      m_i[i] = mn;
      float rs = 0.f;
#pragma unroll
      for (int sub = 0; sub < 4; ++sub) {
        float pv = __expf(sc[sub][i] - mn);
        sc[sub][i] = pv;
        rs += pv;
      }
#pragma unroll
      for (int off = 1; off < 16; off <<= 1) rs += __shfl_xor(rs, off);
      l_i[i] = l_i[i] * al + rs;
#pragma unroll
      for (int n = 0; n < 4; ++n) o[n][i] *= al;
    }

    unsigned short* pw = lP[wave];
#pragma unroll
    for (int sub = 0; sub < 4; ++sub)
#pragma unroll
      for (int i = 0; i < 4; ++i)
        pw[(quad * 4 + i) * LKS + sub * 16 + l15] = f2bf(sc[sub][i]);

    const unsigned short* pr = pw + l15 * LKS + quad * 8;
    short8 pa0 = *(const short8*)(pr);
    short8 pa1 = *(const short8*)(pr + 32);

#pragma unroll
    for (int n = 0; n < 4; ++n) {
      const unsigned short* vr = lV + (n * 16 + l15) * LKS + quad * 8;
      short8 vb0 = *(const short8*)(vr);
      short8 vb1 = *(const short8*)(vr + 32);
      o[n] = __builtin_amdgcn_mfma_f32_16x16x32_bf16(pa0, vb0, o[n], 0, 0, 0);
      o[n] = __builtin_amdgcn_mfma_f32_16x16x32_bf16(pa1, vb1, o[n], 0, 0, 0);
    }
    __syncthreads();
  }

  int b = bh >> 4, h = bh & 15;
#pragma unroll
  for (int i = 0; i < 4; ++i) {
    float inv = 1.f / l_i[i];
    int s = qbase + wave * 16 + quad * 4 + i;
    size_t orow = (size_t)(b * 2048 + s) * 1024 + h * 64;
#pragma unroll
    for (int n = 0; n < 4; ++n)
      Oc[orow + n * 16 + l15] = f2bf(o[n][i] * inv);
  }
}

// ---------------------------------------------------------------------------
extern "C" void kernel_launch(void* const* d_in, const int* in_sizes, int n_in,
                              void* d_out, int out_size, void* d_ws, size_t ws_size,
                              hipStream_t stream) {
  const float* x  = (const float*)d_in[0];
  const int* tokpos = (const int*)d_in[1];
  const float* Wq = (const float*)d_in[2];
  const float* Wk = (const float*)d_in[3];
  const float* Wv = (const float*)d_in[4];
  const float* Wo = (const float*)d_in[5];
  float* out = (float*)d_out;

  // Workspace: ctab|stab fp32 (64K each), then bf16 region:
  // Qb,Kb,Vb,Oc,xb (4M elems each) | Wqb,Wkb,Wvb,Wob (1M each)  ~49 MB
  float* ws = (float*)d_ws;
  float* ctab = ws;
  float* stab = ctab + 65536;
  unsigned short* u = (unsigned short*)(stab + 65536);
  unsigned short* Qb  = u;
  unsigned short* Kb  = Qb + 4194304;
  unsigned short* Vb  = Kb + 4194304;   // transposed [bh][d][s]
  unsigned short* Oc  = Vb + 4194304;
  unsigned short* xb  = Oc + 4194304;
  unsigned short* Wqb = xb + 4194304;
  unsigned short* Wkb = Wqb + 1048576;
  unsigned short* Wvb = Wkb + 1048576;
  unsigned short* Wob = Wvb + 1048576;

  cvt_bf16<<<4096, 256, 0, stream>>>((const float4*)x,  (ushort4*)xb,  1048576);
  cvt_bf16<<<1024, 256, 0, stream>>>((const float4*)Wq, (ushort4*)Wqb, 262144);
  cvt_bf16<<<1024, 256, 0, stream>>>((const float4*)Wk, (ushort4*)Wkb, 262144);
  cvt_bf16<<<1024, 256, 0, stream>>>((const float4*)Wv, (ushort4*)Wvb, 262144);
  cvt_bf16<<<1024, 256, 0, stream>>>((const float4*)Wo, (ushort4*)Wob, 262144);

  rope_tables<<<256, 256, 0, stream>>>(tokpos, ctab, stab);
  qkv_mfma<<<dim3(32, 8, 3), 256, 0, stream>>>(
      xb, Wqb, Wkb, Wvb, ctab, stab, Qb, Kb, Vb);
  attn_flash<<<dim3(32, 32), 256, 0, stream>>>(Qb, Kb, Vb, Oc);
  oproj_mfma<<<dim3(32, 8), 256, 0, stream>>>(Oc, Wob, out);
}

// Round 5
// 245.122 us; speedup vs baseline: 11.7996x; 1.2142x over previous
//
#include <hip/hip_runtime.h>
#include <hip/hip_bf16.h>

// B=2, S=2048, D=1024, H=16, DK=64, THETA=10000
// Inputs fp32 (positions int32): x[2,2048,1024], token_positions[2048],
// Wq,Wk,Wv,Wo [1024,1024].  Output fp32 [2,2048,1024].
// proj: y[b,s,o] = sum_d x[b,s,d] * W[o,d]

typedef __attribute__((ext_vector_type(8))) short short8;   // 8 bf16 = 4 VGPRs
typedef __attribute__((ext_vector_type(4))) float floatx4;  // MFMA accumulator

static __device__ __forceinline__ unsigned short f2bf(float f) {
  __hip_bfloat16 h = __float2bfloat16(f);
  return *(unsigned short*)&h;
}

#define LSTR 72  // LDS row stride (elements): 144B -> 2-way bank alias on reads (free)

// ---------------------------------------------------------------------------
// fp32 -> bf16 conversion, all 5 tensors in one launch (blockIdx.y selects)
// ---------------------------------------------------------------------------
__global__ __launch_bounds__(256) void cvt_all(
    const float4* __restrict__ x,  const float4* __restrict__ wq,
    const float4* __restrict__ wk, const float4* __restrict__ wv,
    const float4* __restrict__ wo,
    ushort4* __restrict__ xb,  ushort4* __restrict__ wqb,
    ushort4* __restrict__ wkb, ushort4* __restrict__ wvb,
    ushort4* __restrict__ wob) {
  int t = blockIdx.y;
  const float4* s = (t == 0) ? x : (t == 1) ? wq : (t == 2) ? wk : (t == 3) ? wv : wo;
  ushort4* d = (t == 0) ? xb : (t == 1) ? wqb : (t == 2) ? wkb : (t == 3) ? wvb : wob;
  int n4 = (t == 0) ? 1048576 : 262144;
  int i = blockIdx.x * 256 + threadIdx.x;
  if (i < n4) {
    float4 v = s[i];
    ushort4 o;
    o.x = f2bf(v.x); o.y = f2bf(v.y); o.z = f2bf(v.z); o.w = f2bf(v.w);
    d[i] = o;
  }
}

// ---------------------------------------------------------------------------
// RoPE cos/sin tables, fp32, [s][pair 0..31]
// ---------------------------------------------------------------------------
__global__ void rope_tables(const int* __restrict__ tokpos,
                            float* __restrict__ ctab, float* __restrict__ stab) {
  int idx = blockIdx.x * 256 + threadIdx.x;  // 65536
  int s = idx >> 5;
  int i = idx & 31;
  float inv = expf(-9.210340371976184f * (float)(2 * i) / 64.0f);
  float ang = (float)tokpos[s] * inv;
  ctab[idx] = cosf(ang);
  stab[idx] = sinf(ang);
}

// ---------------------------------------------------------------------------
// Shared 128x128-tile GEMM body (m93 structure), BK=64, LDS staged.
// ---------------------------------------------------------------------------
#define GEMM128_BODY(Aptr, Wptr, m0, n0)                                        \
  __shared__ unsigned short lA[128 * LSTR];                                     \
  __shared__ unsigned short lB[128 * LSTR];                                     \
  int tid = threadIdx.x;                                                        \
  int wave = tid >> 6, lane = tid & 63;                                         \
  int wm = wave >> 1, wn = wave & 1;                                            \
  int l15 = lane & 15, quad = lane >> 4;                                        \
  floatx4 acc[4][4];                                                            \
  _Pragma("unroll") for (int m = 0; m < 4; ++m)                                 \
      _Pragma("unroll") for (int n = 0; n < 4; ++n)                             \
          acc[m][n] = (floatx4){0.f, 0.f, 0.f, 0.f};                            \
  for (int kt = 0; kt < 16; ++kt) {                                             \
    _Pragma("unroll") for (int p = 0; p < 4; ++p) {                             \
      int c = p * 256 + tid;            /* 0..1023: 128 rows x 8 chunks */      \
      int r = c >> 3, ch = (c & 7) * 8;                                         \
      *(short8*)(lA + r * LSTR + ch) =                                          \
          *(const short8*)(Aptr + (size_t)(m0 + r) * 1024 + kt * 64 + ch);      \
      *(short8*)(lB + r * LSTR + ch) =                                          \
          *(const short8*)(Wptr + (size_t)(n0 + r) * 1024 + kt * 64 + ch);      \
    }                                                                           \
    __syncthreads();                                                            \
    _Pragma("unroll") for (int ks = 0; ks < 2; ++ks) {                          \
      short8 af[4], bf[4];                                                      \
      _Pragma("unroll") for (int m = 0; m < 4; ++m)                             \
          af[m] = *(const short8*)(lA + (wm * 64 + m * 16 + l15) * LSTR +       \
                                   ks * 32 + quad * 8);                         \
      _Pragma("unroll") for (int n = 0; n < 4; ++n)                             \
          bf[n] = *(const short8*)(lB + (wn * 64 + n * 16 + l15) * LSTR +       \
                                   ks * 32 + quad * 8);                         \
      _Pragma("unroll") for (int m = 0; m < 4; ++m)                             \
          _Pragma("unroll") for (int n = 0; n < 4; ++n)                         \
              acc[m][n] = __builtin_amdgcn_mfma_f32_16x16x32_bf16(              \
                  af[m], bf[n], acc[m][n], 0, 0, 0);                            \
    }                                                                           \
    __syncthreads();                                                            \
  }

// ---------------------------------------------------------------------------
// QKV projection, tiled MFMA GEMM + fused RoPE epilogue.
// Q pre-scaled by 1/sqrt(64). Q,K bf16 [bh][s][64]; V transposed [bh][d][2048].
// ---------------------------------------------------------------------------
__global__ __launch_bounds__(256) void qkv_mfma(
    const unsigned short* __restrict__ X,
    const unsigned short* __restrict__ Wq,
    const unsigned short* __restrict__ Wk,
    const unsigned short* __restrict__ Wv,
    const float* __restrict__ ctab, const float* __restrict__ stab,
    unsigned short* __restrict__ Qo, unsigned short* __restrict__ Ko,
    unsigned short* __restrict__ Vo) {
  int mat = blockIdx.z;  // 0=q 1=k 2=v
  const unsigned short* W = (mat == 0) ? Wq : ((mat == 1) ? Wk : Wv);
  unsigned short* Out = (mat == 0) ? Qo : ((mat == 1) ? Ko : Vo);
  int m0 = blockIdx.x * 128, n0 = blockIdx.y * 128;

  GEMM128_BODY(X, W, m0, n0)

#pragma unroll
  for (int n = 0; n < 4; ++n) {
    int col = n0 + wn * 64 + n * 16 + l15;  // 0..1023
    int h = col >> 6;
    int d = col & 63;
    int pi = d >> 1;
    bool odd = (d & 1) != 0;
    size_t hb = (size_t)h * 2048 * 64;
#pragma unroll
    for (int m = 0; m < 4; ++m) {
#pragma unroll
      for (int i = 0; i < 4; ++i) {
        int row = m0 + wm * 64 + m * 16 + quad * 4 + i;
        int b = row >> 11;
        int s = row & 2047;
        float v = acc[m][n][i];
        float res;
        if (mat == 2) {
          res = v;
        } else {
          float p = __shfl_xor(v, 1);
          float c = ctab[s * 32 + pi];
          float sn = stab[s * 32 + pi];
          res = odd ? fmaf(p, sn, v * c) : fmaf(v, c, -p * sn);
          if (mat == 0) res *= 0.125f;  // fold 1/sqrt(dk) into Q
        }
        size_t base = (size_t)b * 16 * 2048 * 64 + hb;
        size_t idx = (mat == 2) ? (base + (size_t)d * 2048 + s)
                                : (base + (size_t)s * 64 + d);
        Out[idx] = f2bf(res);
      }
    }
  }
}

// ---------------------------------------------------------------------------
// Output projection: out = Oc @ Wo^T, tiled MFMA GEMM, fp32 store
// ---------------------------------------------------------------------------
__global__ __launch_bounds__(256) void oproj_mfma(
    const unsigned short* __restrict__ A, const unsigned short* __restrict__ Wo,
    float* __restrict__ Out) {
  int m0 = blockIdx.x * 128, n0 = blockIdx.y * 128;

  GEMM128_BODY(A, Wo, m0, n0)

#pragma unroll
  for (int m = 0; m < 4; ++m) {
#pragma unroll
    for (int n = 0; n < 4; ++n) {
      int col = n0 + wn * 64 + n * 16 + l15;
#pragma unroll
      for (int i = 0; i < 4; ++i) {
        int row = m0 + wm * 64 + m * 16 + quad * 4 + i;
        Out[(size_t)row * 1024 + col] = acc[m][n][i];
      }
    }
  }
}

// ---------------------------------------------------------------------------
// Flash attention, transposed-score form.
//  S^T = K·Q^T  -> per-lane q (= lane&15): softmax is in-lane + 2 shfl_xor.
//  O^T = V^T·P^T -> per-lane q: alpha-rescale and 1/l are pure per-lane.
// Register-prefetch double buffering for K/V staging.
// Q,K: bf16 [bh][s][64] (Q pre-scaled); Vt: bf16 [bh][d][2048]; Oc: [b*s][1024].
// ---------------------------------------------------------------------------
#define LKS 72

__global__ __launch_bounds__(256) void attn_flash(
    const unsigned short* __restrict__ Q, const unsigned short* __restrict__ K,
    const unsigned short* __restrict__ Vt, unsigned short* __restrict__ Oc) {
  __shared__ unsigned short lK[64 * LKS];      // [kj][d]
  __shared__ unsigned short lV[64 * LKS];      // [d][kj]
  __shared__ unsigned short lP[4][16 * LKS];   // per-wave [q][kj]

  int tid = threadIdx.x;
  int wave = tid >> 6, lane = tid & 63;
  int l15 = lane & 15, quad = lane >> 4;
  int qtile = 31 - blockIdx.x;   // heavy tiles dispatch first
  int bh = blockIdx.y;
  size_t base = (size_t)bh * 2048 * 64;
  int qbase = qtile * 64;

  // Q rows as B-operand fragments (B[k=d][n=q]); q = wavebase + l15
  const unsigned short* qrow = Q + base + (size_t)(qbase + wave * 16 + l15) * 64;
  short8 qb0 = *(const short8*)(qrow + quad * 8);
  short8 qb1 = *(const short8*)(qrow + 32 + quad * 8);

  floatx4 o[4];          // O^T[d = n*16+quad*4+reg][q = l15]
  float m_i = -1e30f, l_i = 0.f;   // per-lane softmax state (q = l15)
#pragma unroll
  for (int n = 0; n < 4; ++n) o[n] = (floatx4){0.f, 0.f, 0.f, 0.f};

  // staging slots: thread covers rows r0,r1, chunk e0
  int r0 = tid >> 3, e0 = (tid & 7) * 8;
  int r1 = r0 + 32;

  // prefetch kt=0
  const unsigned short* kp = K + base;
  const unsigned short* vp = Vt + base;
  short8 pk0 = *(const short8*)(kp + r0 * 64 + e0);
  short8 pk1 = *(const short8*)(kp + r1 * 64 + e0);
  short8 pv0 = *(const short8*)(vp + (size_t)r0 * 2048 + e0);
  short8 pv1 = *(const short8*)(vp + (size_t)r1 * 2048 + e0);

  for (int kt = 0; kt <= qtile; ++kt) {
    __syncthreads();   // all waves done reading lK/lV from previous iter
    *(short8*)(lK + r0 * LKS + e0) = pk0;
    *(short8*)(lK + r1 * LKS + e0) = pk1;
    *(short8*)(lV + r0 * LKS + e0) = pv0;
    *(short8*)(lV + r1 * LKS + e0) = pv1;
    __syncthreads();

    if (kt < qtile) {  // prefetch next tile; consumed at next iter's LDS write
      const unsigned short* kn = K + base + (size_t)(kt + 1) * 64 * 64;
      const unsigned short* vn = Vt + base + (kt + 1) * 64;
      pk0 = *(const short8*)(kn + r0 * 64 + e0);
      pk1 = *(const short8*)(kn + r1 * 64 + e0);
      pv0 = *(const short8*)(vn + (size_t)r0 * 2048 + e0);
      pv1 = *(const short8*)(vn + (size_t)r1 * 2048 + e0);
    }

    // ---- S^T = K·Q^T : A = K rows, B = Q rows.  sc[sub][i] is score for
    //      kpos = sub*16 + quad*4 + i, q = l15 (within wave tile).
    float sc[4][4];
#pragma unroll
    for (int sub = 0; sub < 4; ++sub) {
      const unsigned short* kr = lK + (sub * 16 + l15) * LKS + quad * 8;
      short8 a0 = *(const short8*)(kr);
      short8 a1 = *(const short8*)(kr + 32);
      floatx4 s = {0.f, 0.f, 0.f, 0.f};
      s = __builtin_amdgcn_mfma_f32_16x16x32_bf16(a0, qb0, s, 0, 0, 0);
      s = __builtin_amdgcn_mfma_f32_16x16x32_bf16(a1, qb1, s, 0, 0, 0);
#pragma unroll
      for (int i = 0; i < 4; ++i) sc[sub][i] = s[i];
    }

    // ---- causal mask (diagonal tile only): k-within > q-within
    if (kt == qtile) {
      int qin = wave * 16 + l15;
#pragma unroll
      for (int sub = 0; sub < 4; ++sub)
#pragma unroll
        for (int i = 0; i < 4; ++i)
          if (sub * 16 + quad * 4 + i > qin) sc[sub][i] = -1e30f;
    }

    // ---- online softmax: in-lane tree + 2 cross-quad shuffles
    float mb = sc[0][0];
#pragma unroll
    for (int sub = 0; sub < 4; ++sub)
#pragma unroll
      for (int i = 0; i < 4; ++i) mb = fmaxf(mb, sc[sub][i]);
    mb = fmaxf(mb, __shfl_xor(mb, 16));
    mb = fmaxf(mb, __shfl_xor(mb, 32));

    float mn = fmaxf(m_i, mb);
    float al = __expf(m_i - mn);
    m_i = mn;
    float rs = 0.f;
#pragma unroll
    for (int sub = 0; sub < 4; ++sub)
#pragma unroll
      for (int i = 0; i < 4; ++i) {
        float p = __expf(sc[sub][i] - mn);
        sc[sub][i] = p;
        rs += p;
      }
    rs += __shfl_xor(rs, 16);
    rs += __shfl_xor(rs, 32);
    l_i = l_i * al + rs;

    // per-lane rescale of O^T columns (q = l15 matches softmax state)
#pragma unroll
    for (int n = 0; n < 4; ++n) {
      o[n][0] *= al; o[n][1] *= al; o[n][2] *= al; o[n][3] *= al;
    }

    // ---- P^T -> lP as [q][k] rows, packed 4-wide (consecutive i = consecutive k)
    unsigned short* pw = lP[wave];
#pragma unroll
    for (int sub = 0; sub < 4; ++sub) {
      ushort4 pq;
      pq.x = f2bf(sc[sub][0]); pq.y = f2bf(sc[sub][1]);
      pq.z = f2bf(sc[sub][2]); pq.w = f2bf(sc[sub][3]);
      *(ushort4*)(pw + l15 * LKS + sub * 16 + quad * 4) = pq;
    }

    const unsigned short* pr = pw + l15 * LKS + quad * 8;
    short8 pa0 = *(const short8*)(pr);
    short8 pa1 = *(const short8*)(pr + 32);

    // ---- O^T += V^T·P^T : A = lV rows (d), B = lP rows (q)
#pragma unroll
    for (int n = 0; n < 4; ++n) {
      const unsigned short* vr = lV + (n * 16 + l15) * LKS + quad * 8;
      short8 vb0 = *(const short8*)(vr);
      short8 vb1 = *(const short8*)(vr + 32);
      o[n] = __builtin_amdgcn_mfma_f32_16x16x32_bf16(vb0, pa0, o[n], 0, 0, 0);
      o[n] = __builtin_amdgcn_mfma_f32_16x16x32_bf16(vb1, pa1, o[n], 0, 0, 0);
    }
  }

  // ---- epilogue: per-lane 1/l, packed stores; lane owns row s = qbase+wave*16+l15
  int b = bh >> 4, h = bh & 15;
  float inv = 1.f / l_i;
  int s = qbase + wave * 16 + l15;
  size_t orow = (size_t)(b * 2048 + s) * 1024 + h * 64;
#pragma unroll
  for (int n = 0; n < 4; ++n) {
    ushort4 ov;
    ov.x = f2bf(o[n][0] * inv);
    ov.y = f2bf(o[n][1] * inv);
    ov.z = f2bf(o[n][2] * inv);
    ov.w = f2bf(o[n][3] * inv);
    *(ushort4*)(Oc + orow + n * 16 + quad * 4) = ov;
  }
}

// ---------------------------------------------------------------------------
extern "C" void kernel_launch(void* const* d_in, const int* in_sizes, int n_in,
                              void* d_out, int out_size, void* d_ws, size_t ws_size,
                              hipStream_t stream) {
  const float* x  = (const float*)d_in[0];
  const int* tokpos = (const int*)d_in[1];
  const float* Wq = (const float*)d_in[2];
  const float* Wk = (const float*)d_in[3];
  const float* Wv = (const float*)d_in[4];
  const float* Wo = (const float*)d_in[5];
  float* out = (float*)d_out;

  float* ws = (float*)d_ws;
  float* ctab = ws;
  float* stab = ctab + 65536;
  unsigned short* u = (unsigned short*)(stab + 65536);
  unsigned short* Qb  = u;
  unsigned short* Kb  = Qb + 4194304;
  unsigned short* Vb  = Kb + 4194304;   // transposed [bh][d][s]
  unsigned short* Oc  = Vb + 4194304;
  unsigned short* xb  = Oc + 4194304;
  unsigned short* Wqb = xb + 4194304;
  unsigned short* Wkb = Wqb + 1048576;
  unsigned short* Wvb = Wkb + 1048576;
  unsigned short* Wob = Wvb + 1048576;

  cvt_all<<<dim3(4096, 5), 256, 0, stream>>>(
      (const float4*)x, (const float4*)Wq, (const float4*)Wk,
      (const float4*)Wv, (const float4*)Wo,
      (ushort4*)xb, (ushort4*)Wqb, (ushort4*)Wkb, (ushort4*)Wvb, (ushort4*)Wob);

  rope_tables<<<256, 256, 0, stream>>>(tokpos, ctab, stab);
  qkv_mfma<<<dim3(32, 8, 3), 256, 0, stream>>>(
      xb, Wqb, Wkb, Wvb, ctab, stab, Qb, Kb, Vb);
  attn_flash<<<dim3(32, 32), 256, 0, stream>>>(Qb, Kb, Vb, Oc);
  oproj_mfma<<<dim3(32, 8), 256, 0, stream>>>(Oc, Wob, out);
}

// Round 6
// 198.996 us; speedup vs baseline: 14.5347x; 1.2318x over previous
//
#include <hip/hip_runtime.h>
#include <hip/hip_bf16.h>

// B=2, S=2048, D=1024, H=16, DK=64, THETA=10000
// Inputs fp32 (positions int32): x[2,2048,1024], token_positions[2048],
// Wq,Wk,Wv,Wo [1024,1024].  Output fp32 [2,2048,1024].
// proj: y[b,s,o] = sum_d x[b,s,d] * W[o,d]

typedef __attribute__((ext_vector_type(8))) short short8;   // 8 bf16 = 4 VGPRs
typedef __attribute__((ext_vector_type(4))) float floatx4;  // MFMA accumulator

static __device__ __forceinline__ unsigned short f2bf(float f) {
  __hip_bfloat16 h = __float2bfloat16(f);
  return *(unsigned short*)&h;
}

#define LSTR 72  // LDS row stride (elements): 144B -> 2-way bank alias on reads (free)

// ---------------------------------------------------------------------------
// fp32 -> bf16 conversion, all 5 tensors in one launch (blockIdx.y selects)
// ---------------------------------------------------------------------------
__global__ __launch_bounds__(256) void cvt_all(
    const float4* __restrict__ x,  const float4* __restrict__ wq,
    const float4* __restrict__ wk, const float4* __restrict__ wv,
    const float4* __restrict__ wo,
    ushort4* __restrict__ xb,  ushort4* __restrict__ wqb,
    ushort4* __restrict__ wkb, ushort4* __restrict__ wvb,
    ushort4* __restrict__ wob) {
  int t = blockIdx.y;
  const float4* s = (t == 0) ? x : (t == 1) ? wq : (t == 2) ? wk : (t == 3) ? wv : wo;
  ushort4* d = (t == 0) ? xb : (t == 1) ? wqb : (t == 2) ? wkb : (t == 3) ? wvb : wob;
  int n4 = (t == 0) ? 1048576 : 262144;
  int i = blockIdx.x * 256 + threadIdx.x;
  if (i < n4) {
    float4 v = s[i];
    ushort4 o;
    o.x = f2bf(v.x); o.y = f2bf(v.y); o.z = f2bf(v.z); o.w = f2bf(v.w);
    d[i] = o;
  }
}

// ---------------------------------------------------------------------------
// RoPE cos/sin tables, fp32, [s][pair 0..31]
// ---------------------------------------------------------------------------
__global__ void rope_tables(const int* __restrict__ tokpos,
                            float* __restrict__ ctab, float* __restrict__ stab) {
  int idx = blockIdx.x * 256 + threadIdx.x;  // 65536
  int s = idx >> 5;
  int i = idx & 31;
  float inv = expf(-9.210340371976184f * (float)(2 * i) / 64.0f);
  float ang = (float)tokpos[s] * inv;
  ctab[idx] = cosf(ang);
  stab[idx] = sinf(ang);
}

// ---------------------------------------------------------------------------
// Shared 128x128-tile GEMM body (m93 structure), BK=64, LDS staged.
// ---------------------------------------------------------------------------
#define GEMM128_BODY(Aptr, Wptr, m0, n0)                                        \
  __shared__ unsigned short lA[128 * LSTR];                                     \
  __shared__ unsigned short lB[128 * LSTR];                                     \
  int tid = threadIdx.x;                                                        \
  int wave = tid >> 6, lane = tid & 63;                                         \
  int wm = wave >> 1, wn = wave & 1;                                            \
  int l15 = lane & 15, quad = lane >> 4;                                        \
  floatx4 acc[4][4];                                                            \
  _Pragma("unroll") for (int m = 0; m < 4; ++m)                                 \
      _Pragma("unroll") for (int n = 0; n < 4; ++n)                             \
          acc[m][n] = (floatx4){0.f, 0.f, 0.f, 0.f};                            \
  for (int kt = 0; kt < 16; ++kt) {                                             \
    _Pragma("unroll") for (int p = 0; p < 4; ++p) {                             \
      int c = p * 256 + tid;            /* 0..1023: 128 rows x 8 chunks */      \
      int r = c >> 3, ch = (c & 7) * 8;                                         \
      *(short8*)(lA + r * LSTR + ch) =                                          \
          *(const short8*)(Aptr + (size_t)(m0 + r) * 1024 + kt * 64 + ch);      \
      *(short8*)(lB + r * LSTR + ch) =                                          \
          *(const short8*)(Wptr + (size_t)(n0 + r) * 1024 + kt * 64 + ch);      \
    }                                                                           \
    __syncthreads();                                                            \
    _Pragma("unroll") for (int ks = 0; ks < 2; ++ks) {                          \
      short8 af[4], bf[4];                                                      \
      _Pragma("unroll") for (int m = 0; m < 4; ++m)                             \
          af[m] = *(const short8*)(lA + (wm * 64 + m * 16 + l15) * LSTR +       \
                                   ks * 32 + quad * 8);                         \
      _Pragma("unroll") for (int n = 0; n < 4; ++n)                             \
          bf[n] = *(const short8*)(lB + (wn * 64 + n * 16 + l15) * LSTR +       \
                                   ks * 32 + quad * 8);                         \
      _Pragma("unroll") for (int m = 0; m < 4; ++m)                             \
          _Pragma("unroll") for (int n = 0; n < 4; ++n)                         \
              acc[m][n] = __builtin_amdgcn_mfma_f32_16x16x32_bf16(              \
                  af[m], bf[n], acc[m][n], 0, 0, 0);                            \
    }                                                                           \
    __syncthreads();                                                            \
  }

// ---------------------------------------------------------------------------
// QKV projection, tiled MFMA GEMM + fused RoPE epilogue.
// Q pre-scaled by 1/sqrt(64). Q,K bf16 [bh][s][64]; V transposed [bh][d][2048].
// ---------------------------------------------------------------------------
__global__ __launch_bounds__(256) void qkv_mfma(
    const unsigned short* __restrict__ X,
    const unsigned short* __restrict__ Wq,
    const unsigned short* __restrict__ Wk,
    const unsigned short* __restrict__ Wv,
    const float* __restrict__ ctab, const float* __restrict__ stab,
    unsigned short* __restrict__ Qo, unsigned short* __restrict__ Ko,
    unsigned short* __restrict__ Vo) {
  int mat = blockIdx.z;  // 0=q 1=k 2=v
  const unsigned short* W = (mat == 0) ? Wq : ((mat == 1) ? Wk : Wv);
  unsigned short* Out = (mat == 0) ? Qo : ((mat == 1) ? Ko : Vo);
  int m0 = blockIdx.x * 128, n0 = blockIdx.y * 128;

  GEMM128_BODY(X, W, m0, n0)

#pragma unroll
  for (int n = 0; n < 4; ++n) {
    int col = n0 + wn * 64 + n * 16 + l15;  // 0..1023
    int h = col >> 6;
    int d = col & 63;
    int pi = d >> 1;
    bool odd = (d & 1) != 0;
    size_t hb = (size_t)h * 2048 * 64;
#pragma unroll
    for (int m = 0; m < 4; ++m) {
      int row0 = m0 + wm * 64 + m * 16 + quad * 4;  // aligned 4; rows row0..row0+3
      int b = row0 >> 11;
      int s0 = row0 & 2047;
      size_t base = (size_t)b * 16 * 2048 * 64 + hb;
      if (mat == 2) {
        // V: packed b64 store along s (transposed layout [d][s])
        ushort4 pv;
        pv.x = f2bf(acc[m][n][0]);
        pv.y = f2bf(acc[m][n][1]);
        pv.z = f2bf(acc[m][n][2]);
        pv.w = f2bf(acc[m][n][3]);
        *(ushort4*)(Out + base + (size_t)d * 2048 + s0) = pv;
      } else {
#pragma unroll
        for (int i = 0; i < 4; ++i) {
          int s = s0 + i;
          float v = acc[m][n][i];
          float p = __shfl_xor(v, 1);
          float c = ctab[s * 32 + pi];
          float sn = stab[s * 32 + pi];
          float res = odd ? fmaf(p, sn, v * c) : fmaf(v, c, -p * sn);
          if (mat == 0) res *= 0.125f;  // fold 1/sqrt(dk) into Q
          Out[base + (size_t)s * 64 + d] = f2bf(res);
        }
      }
    }
  }
}

// ---------------------------------------------------------------------------
// Output projection: out = Oc @ Wo^T, tiled MFMA GEMM, fp32 store
// ---------------------------------------------------------------------------
__global__ __launch_bounds__(256) void oproj_mfma(
    const unsigned short* __restrict__ A, const unsigned short* __restrict__ Wo,
    float* __restrict__ Out) {
  int m0 = blockIdx.x * 128, n0 = blockIdx.y * 128;

  GEMM128_BODY(A, Wo, m0, n0)

#pragma unroll
  for (int m = 0; m < 4; ++m) {
#pragma unroll
    for (int n = 0; n < 4; ++n) {
      int col = n0 + wn * 64 + n * 16 + l15;
#pragma unroll
      for (int i = 0; i < 4; ++i) {
        int row = m0 + wm * 64 + m * 16 + quad * 4 + i;
        Out[(size_t)row * 1024 + col] = acc[m][n][i];
      }
    }
  }
}

// ---------------------------------------------------------------------------
// Flash attention, transposed-score form + load-balanced (qtile,bh) swizzle.
//  S^T = K·Q^T  -> per-lane q (= lane&15): softmax is in-lane + 2 shfl_xor.
//  O^T = V^T·P^T -> per-lane q: alpha-rescale and 1/l are pure per-lane.
// Swizzle: blocks {id, id+256, id+512, id+768} co-reside on one CU (1024-block
// grid, all resident). qtiles per CU = {x, 31-x, (15-x)&31, (16+x)&31} ->
// exactly 66 tile-iterations per CU for every x (perfect static balance).
// ---------------------------------------------------------------------------
#define LKS 72

__global__ __launch_bounds__(256) void attn_flash(
    const unsigned short* __restrict__ Q, const unsigned short* __restrict__ K,
    const unsigned short* __restrict__ Vt, unsigned short* __restrict__ Oc) {
  __shared__ unsigned short lK[64 * LKS];      // [kj][d]
  __shared__ unsigned short lV[64 * LKS];      // [d][kj]
  __shared__ unsigned short lP[4][16 * LKS];   // per-wave [q][kj]

  int tid = threadIdx.x;
  int wave = tid >> 6, lane = tid & 63;
  int l15 = lane & 15, quad = lane >> 4;

  // load-balance swizzle (bijective (x,y) -> (qtile,bh))
  int xb_ = blockIdx.x;          // 0..31
  int yb_ = blockIdx.y;          // 0..31
  int jb = yb_ >> 3, ib = yb_ & 7;
  int qtile;
  if (jb == 0)      qtile = xb_;
  else if (jb == 1) qtile = 31 - xb_;
  else if (jb == 2) qtile = (15 - xb_) & 31;
  else              qtile = (16 + xb_) & 31;
  int bh = ib * 4 + jb;

  size_t base = (size_t)bh * 2048 * 64;
  int qbase = qtile * 64;

  // Q rows as B-operand fragments (B[k=d][n=q]); q = wavebase + l15
  const unsigned short* qrow = Q + base + (size_t)(qbase + wave * 16 + l15) * 64;
  short8 qb0 = *(const short8*)(qrow + quad * 8);
  short8 qb1 = *(const short8*)(qrow + 32 + quad * 8);

  floatx4 o[4];          // O^T[d = n*16+quad*4+reg][q = l15]
  float m_i = -1e30f, l_i = 0.f;   // per-lane softmax state (q = l15)
#pragma unroll
  for (int n = 0; n < 4; ++n) o[n] = (floatx4){0.f, 0.f, 0.f, 0.f};

  // staging slots: thread covers rows r0,r1, chunk e0
  int r0 = tid >> 3, e0 = (tid & 7) * 8;
  int r1 = r0 + 32;

  // prefetch kt=0
  const unsigned short* kp = K + base;
  const unsigned short* vp = Vt + base;
  short8 pk0 = *(const short8*)(kp + r0 * 64 + e0);
  short8 pk1 = *(const short8*)(kp + r1 * 64 + e0);
  short8 pv0 = *(const short8*)(vp + (size_t)r0 * 2048 + e0);
  short8 pv1 = *(const short8*)(vp + (size_t)r1 * 2048 + e0);

  for (int kt = 0; kt <= qtile; ++kt) {
    __syncthreads();   // all waves done reading lK/lV from previous iter
    *(short8*)(lK + r0 * LKS + e0) = pk0;
    *(short8*)(lK + r1 * LKS + e0) = pk1;
    *(short8*)(lV + r0 * LKS + e0) = pv0;
    *(short8*)(lV + r1 * LKS + e0) = pv1;
    __syncthreads();

    if (kt < qtile) {  // prefetch next tile; consumed at next iter's LDS write
      const unsigned short* kn = K + base + (size_t)(kt + 1) * 64 * 64;
      const unsigned short* vn = Vt + base + (kt + 1) * 64;
      pk0 = *(const short8*)(kn + r0 * 64 + e0);
      pk1 = *(const short8*)(kn + r1 * 64 + e0);
      pv0 = *(const short8*)(vn + (size_t)r0 * 2048 + e0);
      pv1 = *(const short8*)(vn + (size_t)r1 * 2048 + e0);
    }

    // ---- S^T = K·Q^T : A = K rows, B = Q rows.  sc[sub][i] is score for
    //      kpos = sub*16 + quad*4 + i, q = l15 (within wave tile).
    float sc[4][4];
#pragma unroll
    for (int sub = 0; sub < 4; ++sub) {
      const unsigned short* kr = lK + (sub * 16 + l15) * LKS + quad * 8;
      short8 a0 = *(const short8*)(kr);
      short8 a1 = *(const short8*)(kr + 32);
      floatx4 s = {0.f, 0.f, 0.f, 0.f};
      s = __builtin_amdgcn_mfma_f32_16x16x32_bf16(a0, qb0, s, 0, 0, 0);
      s = __builtin_amdgcn_mfma_f32_16x16x32_bf16(a1, qb1, s, 0, 0, 0);
#pragma unroll
      for (int i = 0; i < 4; ++i) sc[sub][i] = s[i];
    }

    // ---- causal mask (diagonal tile only): k-within > q-within
    if (kt == qtile) {
      int qin = wave * 16 + l15;
#pragma unroll
      for (int sub = 0; sub < 4; ++sub)
#pragma unroll
        for (int i = 0; i < 4; ++i)
          if (sub * 16 + quad * 4 + i > qin) sc[sub][i] = -1e30f;
    }

    // ---- online softmax: in-lane tree + 2 cross-quad shuffles
    float mb = sc[0][0];
#pragma unroll
    for (int sub = 0; sub < 4; ++sub)
#pragma unroll
      for (int i = 0; i < 4; ++i) mb = fmaxf(mb, sc[sub][i]);
    mb = fmaxf(mb, __shfl_xor(mb, 16));
    mb = fmaxf(mb, __shfl_xor(mb, 32));

    float mn = fmaxf(m_i, mb);
    float al = __expf(m_i - mn);
    m_i = mn;
    float rs = 0.f;
#pragma unroll
    for (int sub = 0; sub < 4; ++sub)
#pragma unroll
      for (int i = 0; i < 4; ++i) {
        float p = __expf(sc[sub][i] - mn);
        sc[sub][i] = p;
        rs += p;
      }
    rs += __shfl_xor(rs, 16);
    rs += __shfl_xor(rs, 32);
    l_i = l_i * al + rs;

    // per-lane rescale of O^T columns (q = l15 matches softmax state)
#pragma unroll
    for (int n = 0; n < 4; ++n) {
      o[n][0] *= al; o[n][1] *= al; o[n][2] *= al; o[n][3] *= al;
    }

    // ---- P^T -> lP as [q][k] rows, packed 4-wide (consecutive i = consecutive k)
    unsigned short* pw = lP[wave];
#pragma unroll
    for (int sub = 0; sub < 4; ++sub) {
      ushort4 pq;
      pq.x = f2bf(sc[sub][0]); pq.y = f2bf(sc[sub][1]);
      pq.z = f2bf(sc[sub][2]); pq.w = f2bf(sc[sub][3]);
      *(ushort4*)(pw + l15 * LKS + sub * 16 + quad * 4) = pq;
    }

    const unsigned short* pr = pw + l15 * LKS + quad * 8;
    short8 pa0 = *(const short8*)(pr);
    short8 pa1 = *(const short8*)(pr + 32);

    // ---- O^T += V^T·P^T : A = lV rows (d), B = lP rows (q)
#pragma unroll
    for (int n = 0; n < 4; ++n) {
      const unsigned short* vr = lV + (n * 16 + l15) * LKS + quad * 8;
      short8 vb0 = *(const short8*)(vr);
      short8 vb1 = *(const short8*)(vr + 32);
      o[n] = __builtin_amdgcn_mfma_f32_16x16x32_bf16(vb0, pa0, o[n], 0, 0, 0);
      o[n] = __builtin_amdgcn_mfma_f32_16x16x32_bf16(vb1, pa1, o[n], 0, 0, 0);
    }
  }

  // ---- epilogue: per-lane 1/l, packed stores; lane owns row s = qbase+wave*16+l15
  int b = bh >> 4, h = bh & 15;
  float inv = 1.f / l_i;
  int s = qbase + wave * 16 + l15;
  size_t orow = (size_t)(b * 2048 + s) * 1024 + h * 64;
#pragma unroll
  for (int n = 0; n < 4; ++n) {
    ushort4 ov;
    ov.x = f2bf(o[n][0] * inv);
    ov.y = f2bf(o[n][1] * inv);
    ov.z = f2bf(o[n][2] * inv);
    ov.w = f2bf(o[n][3] * inv);
    *(ushort4*)(Oc + orow + n * 16 + quad * 4) = ov;
  }
}

// ---------------------------------------------------------------------------
extern "C" void kernel_launch(void* const* d_in, const int* in_sizes, int n_in,
                              void* d_out, int out_size, void* d_ws, size_t ws_size,
                              hipStream_t stream) {
  const float* x  = (const float*)d_in[0];
  const int* tokpos = (const int*)d_in[1];
  const float* Wq = (const float*)d_in[2];
  const float* Wk = (const float*)d_in[3];
  const float* Wv = (const float*)d_in[4];
  const float* Wo = (const float*)d_in[5];
  float* out = (float*)d_out;

  float* ws = (float*)d_ws;
  float* ctab = ws;
  float* stab = ctab + 65536;
  unsigned short* u = (unsigned short*)(stab + 65536);
  unsigned short* Qb  = u;
  unsigned short* Kb  = Qb + 4194304;
  unsigned short* Vb  = Kb + 4194304;   // transposed [bh][d][s]
  unsigned short* Oc  = Vb + 4194304;
  unsigned short* xb  = Oc + 4194304;
  unsigned short* Wqb = xb + 4194304;
  unsigned short* Wkb = Wqb + 1048576;
  unsigned short* Wvb = Wkb + 1048576;
  unsigned short* Wob = Wvb + 1048576;

  cvt_all<<<dim3(4096, 5), 256, 0, stream>>>(
      (const float4*)x, (const float4*)Wq, (const float4*)Wk,
      (const float4*)Wv, (const float4*)Wo,
      (ushort4*)xb, (ushort4*)Wqb, (ushort4*)Wkb, (ushort4*)Wvb, (ushort4*)Wob);

  rope_tables<<<256, 256, 0, stream>>>(tokpos, ctab, stab);
  qkv_mfma<<<dim3(32, 8, 3), 256, 0, stream>>>(
      xb, Wqb, Wkb, Wvb, ctab, stab, Qb, Kb, Vb);
  attn_flash<<<dim3(32, 32), 256, 0, stream>>>(Qb, Kb, Vb, Oc);
  oproj_mfma<<<dim3(32, 8), 256, 0, stream>>>(Oc, Wob, out);
}